// Round 4
// baseline (260.210 us; speedup 1.0000x reference)
//
#include <hip/hip_runtime.h>
#include <hip/hip_bf16.h>
#include <cstdint>

using bf16 = __hip_bfloat16;
typedef __attribute__((ext_vector_type(8))) short short8;
typedef __attribute__((ext_vector_type(4))) float floatx4;

// Problem constants
static constexpr int BATCH = 8192;
static constexpr int K1    = 2304;   // OBS + NH
static constexpr int N1    = 2048;   // NH
static constexpr int K2    = 2048;   // NH
static constexpr int N2    = 256;    // 2*LAT
static constexpr int KT1   = K1 / 64;  // 36 K-tiles of 64

__device__ __forceinline__ void gload_lds16(const void* g, void* l) {
  __builtin_amdgcn_global_load_lds(
      (const __attribute__((address_space(1))) void*)g,
      (__attribute__((address_space(3))) void*)l, 16, 0, 0);
}

// tanh(x) = 1 - 2/(1+e^{2x}); exp2-based, saturates to +/-1, err ~1e-6
__device__ __forceinline__ float fast_tanh(float x) {
  float e = __builtin_amdgcn_exp2f(x * 2.8853900817779268f);  // 2*log2(e)
  return 1.0f - 2.0f * __builtin_amdgcn_rcpf(e + 1.0f);
}

__device__ __forceinline__ short8 cvt8(const float* src) {
  float4 a = ((const float4*)src)[0];
  float4 b = ((const float4*)src)[1];
  union { short8 v; bf16 e[8]; } u;
  u.e[0] = __float2bfloat16(a.x); u.e[1] = __float2bfloat16(a.y);
  u.e[2] = __float2bfloat16(a.z); u.e[3] = __float2bfloat16(a.w);
  u.e[4] = __float2bfloat16(b.x); u.e[5] = __float2bfloat16(b.y);
  u.e[6] = __float2bfloat16(b.z); u.e[7] = __float2bfloat16(b.w);
  return u.v;
}

// ------- fused prep: cat(x,h)->bf16, W_i2h->bf16, W_h2o->bf16, bias seed ---
static constexpr int SEG0 = BATCH * (K1 / 8);          // 2,359,296
static constexpr int SEG1 = N1 * K1 / 8;               //   589,824
static constexpr int SEG2 = N2 * K2 / 8;               //    65,536
static constexpr int SEG3 = BATCH * (N2 / 4);          //   524,288 (bias seed)
__global__ __launch_bounds__(256) void prep(
    const float* __restrict__ x, const float* __restrict__ h,
    const float* __restrict__ W1, const float* __restrict__ W2,
    const float* __restrict__ b2,
    bf16* __restrict__ comb, bf16* __restrict__ W1b, bf16* __restrict__ W2b,
    float* __restrict__ outp) {
  int i = blockIdx.x * 256 + threadIdx.x;
  if (i < SEG0) {
    int row  = i / 288;
    int slot = i - row * 288;
    const float* src = (slot < 32) ? (x + (size_t)row * 256 + slot * 8)
                                   : (h + (size_t)row * 2048 + (slot - 32) * 8);
    *(short8*)(comb + (size_t)row * 2304 + slot * 8) = cvt8(src);
  } else if (i < SEG0 + SEG1) {
    int j = i - SEG0;
    *(short8*)(W1b + (size_t)j * 8) = cvt8(W1 + (size_t)j * 8);
  } else if (i < SEG0 + SEG1 + SEG2) {
    int j = i - (SEG0 + SEG1);
    *(short8*)(W2b + (size_t)j * 8) = cvt8(W2 + (size_t)j * 8);
  } else {
    int j = i - (SEG0 + SEG1 + SEG2);   // out = bias broadcast (gemm2 seed)
    float4 b = ((const float4*)b2)[j & 63];
    ((float4*)outp)[j] = b;
  }
}

// ---------------- GEMM1: h_new = tanh(A @ W^T + bias) ----------------
// 256x256 tile, BK=64, 8 waves (2M x 4N), 128x64 per wave, 16x16x32 MFMA.
// MERGED-phase schedule: 2 phases per K-tile (was 4). Per phase:
//   [stage A+B half-K-tile (4 gloads)] -> (vmcnt(8) at MP1/MP3) -> s_barrier
//   -> 12 ds_read_b128 (B x4, A-mtg0 x4, A-mtg1 x4; order pinned)
//   -> lgkm(4) -> 16 MFMA (mtg0)        // A-mtg1 reads drain under these
//   -> lgkm(0) -> 16 MFMA (mtg1) -> s_barrier
// Retire protocol (per wave, 4 gloads/phase):
//   prologue stages buf0.kh0, buf0.kh1 <- t0, buf1.kh0 <- t1; vmcnt(4); bar.
//   MP0(cb0,ks0): stage buf1.kh1 <- n+1
//   MP1(cb0,ks1): stage buf0.kh0 <- n+2; vmcnt(8)  [retires buf1.kh0 era]
//   MP2(cb1,ks0): stage buf0.kh1 <- n+2
//   MP3(cb1,ks1): stage buf1.kh0 <- n+3; vmcnt(8)  [retires buf1.kh1, buf0.kh0]
// Every read's source is vmcnt-retired + barrier'd before the read issues;
// every stage's target had its last reader finish >=1 barrier earlier.
// LDS read swizzle term (row>>1)&3 == (r15>>1)&3 (other row terms are
// multiples of 8), so all reads are one per-thread base + immediate offset.
__global__ __launch_bounds__(512, 2) void gemm1_tanh(
    const bf16* __restrict__ A, const bf16* __restrict__ W,
    const float* __restrict__ bias,
    float* __restrict__ hf32, bf16* __restrict__ hb16) {
  __shared__ bf16 lds[2][2][2][8192];   // [buf][A/B][kh][256 rows x 32] 128 KiB
  const int t    = threadIdx.x;         // 0..511
  const int lane = t & 63;
  const int wave = t >> 6;              // 0..7
  const int wm   = (wave >> 2) * 128;   // 0 or 128
  const int wn   = (wave & 3) * 64;     // 0,64,128,192
  const int quad = lane >> 4;
  const int r15  = lane & 15;

  // LDS read bases (byte offsets within one [kh] bank of 16384 B)
  const int swz   = ((quad ^ ((r15 >> 1) & 3)) << 4);
  const int baseA = wm * 64 + r15 * 64 + swz;            // + mtg*4096 + mt*1024
  const int baseB = 32768 + wn * 64 + r15 * 64 + swz;    // + nt*1024

  // staging: thread covers row r = half*128 + (t>>2), 16B slot s = t&3,
  // pre-swizzled global col so LDS dest stays linear (dest = half*8192 + t*16).
  const int srow  = t >> 2;             // 0..127
  const int sslot = t & 3;
  const int sq    = (sslot ^ ((srow >> 1) & 3)) * 8;  // elem offset in K-half

  const size_t Abase = (size_t)blockIdx.x * 256 * K1;
  const size_t Bbase = (size_t)blockIdx.y * 256 * K1;
  const size_t gA0 = Abase + (size_t)srow * K1 + sq;
  const size_t gA1 = Abase + (size_t)(srow + 128) * K1 + sq;
  const size_t gB0 = Bbase + (size_t)srow * K1 + sq;
  const size_t gB1 = Bbase + (size_t)(srow + 128) * K1 + sq;
  const int d0 = t * 16, d1 = 8192 + t * 16;   // LDS byte offsets
  char* const ldsb = (char*)lds;

  // stage A and B halves of (buf sb, K-half skh) from K-tile skt (clamped)
#define STAGE2(sb, skh, skt) do {                                            \
    const int ktc_ = ((skt) < KT1 ? (skt) : (KT1 - 1));                      \
    const size_t ko_ = (size_t)ktc_ * 64 + (skh) * 32;                       \
    char* const la_ = ldsb + ((sb) << 16) + ((skh) << 14);                   \
    gload_lds16(A + gA0 + ko_, la_ + d0);                                    \
    gload_lds16(A + gA1 + ko_, la_ + d1);                                    \
    gload_lds16(W + gB0 + ko_, la_ + 32768 + d0);                            \
    gload_lds16(W + gB1 + ko_, la_ + 32768 + d1);                            \
  } while (0)

  floatx4 acc[8][4];
  const floatx4 z = {0.f, 0.f, 0.f, 0.f};
#pragma unroll
  for (int i = 0; i < 8; i++)
#pragma unroll
    for (int j = 0; j < 4; j++) acc[i][j] = z;

  // prologue: buf0 kh0+kh1 <- tile 0, buf1 kh0 <- tile 1
  STAGE2(0, 0, 0); STAGE2(0, 1, 0); STAGE2(1, 0, 1);
  asm volatile("s_waitcnt vmcnt(4)" ::: "memory");   // buf0 fully landed
  __builtin_amdgcn_s_barrier();

#define MPHASE(cb, ks, sb, skh, skt, VMW) do {                               \
    STAGE2(sb, skh, skt);                                                    \
    __builtin_amdgcn_sched_barrier(0);                                       \
    if (VMW) asm volatile("s_waitcnt vmcnt(8)" ::: "memory");                \
    __builtin_amdgcn_s_barrier();                                            \
    asm volatile("" ::: "memory");  /* no load hoist above barrier */        \
    const char* Lb_ = ldsb + ((cb) << 16) + ((ks) << 14);                    \
    short8 bf_[4], af0_[4], af1_[4];                                         \
    _Pragma("unroll")                                                        \
    for (int nt = 0; nt < 4; ++nt)                                           \
      bf_[nt] = *(const short8*)(Lb_ + baseB + nt * 1024);                   \
    _Pragma("unroll")                                                        \
    for (int mt = 0; mt < 4; ++mt)                                           \
      af0_[mt] = *(const short8*)(Lb_ + baseA + mt * 1024);                  \
    __builtin_amdgcn_sched_barrier(0);                                       \
    _Pragma("unroll")                                                        \
    for (int mt = 0; mt < 4; ++mt)                                           \
      af1_[mt] = *(const short8*)(Lb_ + baseA + 4096 + mt * 1024);           \
    __builtin_amdgcn_sched_barrier(0);                                       \
    asm volatile("s_waitcnt lgkmcnt(4)" ::: "memory");                       \
    __builtin_amdgcn_sched_barrier(0);                                       \
    __builtin_amdgcn_s_setprio(1);                                           \
    _Pragma("unroll")                                                        \
    for (int mt = 0; mt < 4; ++mt)                                           \
      _Pragma("unroll")                                                      \
      for (int nt = 0; nt < 4; ++nt)                                         \
        acc[mt][nt] = __builtin_amdgcn_mfma_f32_16x16x32_bf16(               \
            af0_[mt], bf_[nt], acc[mt][nt], 0, 0, 0);                        \
    __builtin_amdgcn_s_setprio(0);                                           \
    asm volatile("s_waitcnt lgkmcnt(0)" ::: "memory");                       \
    __builtin_amdgcn_sched_barrier(0);                                       \
    __builtin_amdgcn_s_setprio(1);                                           \
    _Pragma("unroll")                                                        \
    for (int mt = 0; mt < 4; ++mt)                                           \
      _Pragma("unroll")                                                      \
      for (int nt = 0; nt < 4; ++nt)                                         \
        acc[4 + mt][nt] = __builtin_amdgcn_mfma_f32_16x16x32_bf16(           \
            af1_[mt], bf_[nt], acc[4 + mt][nt], 0, 0, 0);                    \
    __builtin_amdgcn_s_setprio(0);                                           \
    __builtin_amdgcn_s_barrier();                                            \
  } while (0)

#pragma clang loop unroll(disable)
  for (int t2 = 0; t2 < KT1 / 2; ++t2) {
    const int n = 2 * t2;
    MPHASE(0, 0,  1, 1, n + 1, 0);
    MPHASE(0, 1,  0, 0, n + 2, 1);
    MPHASE(1, 0,  0, 1, n + 2, 0);
    MPHASE(1, 1,  1, 0, n + 3, 1);
  }
#undef MPHASE
#undef STAGE2

  // epilogue: bias + fast tanh, dual-write f32 (output) and bf16 (GEMM2 input)
  const int gcol0 = blockIdx.y * 256 + wn;
  float bv[4];
#pragma unroll
  for (int nt = 0; nt < 4; ++nt) bv[nt] = bias[gcol0 + nt * 16 + r15];
  const size_t grow0 = (size_t)blockIdx.x * 256 + wm;
#pragma unroll
  for (int mt = 0; mt < 8; ++mt) {
#pragma unroll
    for (int i = 0; i < 4; ++i) {
      const size_t gr = grow0 + mt * 16 + quad * 4 + i;
      const size_t rb = gr * (size_t)N1;
#pragma unroll
      for (int nt = 0; nt < 4; ++nt) {
        const int gc = gcol0 + nt * 16 + r15;
        float v = fast_tanh(acc[mt][nt][i] + bv[nt]);
        hf32[rb + gc] = v;
        hb16[rb + gc] = __float2bfloat16(v);
      }
    }
  }
}

// ---------------- GEMM2: out += h_new @ W_h2o^T (split-K=2) -------------
// Double-buffered: stage(next) issued before compute(cur); counted vmcnt(9)
// (never 0 mid-loop) + raw barriers so prefetch stays in flight.
__global__ __launch_bounds__(256) void gemm2_out(
    const bf16* __restrict__ A, const bf16* __restrict__ W,
    float* __restrict__ out) {
  __shared__ bf16 As[2][32 * 64];    //  8 KB
  __shared__ bf16 Bs[2][256 * 64];   // 64 KB
  const int t    = threadIdx.x;
  const int lane = t & 63;
  const int wave = t >> 6;
  const int quad = lane >> 4;
  const int r15  = lane & 15;
  const int srow = t >> 3;   // 0..31
  const int sc   = t & 7;

  const int mrow0 = blockIdx.x * 32;
  const int kbase = blockIdx.y * (K2 / 2);   // 0 or 1024

#define G2STAGE(b, kt) do {                                                  \
    const int k0_ = kbase + (kt) * 64;                                       \
    {                                                                        \
      int gc_ = k0_ + ((sc ^ (srow & 7)) << 3);                              \
      gload_lds16(A + (size_t)(mrow0 + srow) * K2 + gc_,                     \
                  (char*)As[b] + t * 16);                                    \
    }                                                                        \
    _Pragma("unroll")                                                        \
    for (int it = 0; it < 8; ++it) {                                         \
      int row_ = it * 32 + srow;                                             \
      int gc_  = k0_ + ((sc ^ (row_ & 7)) << 3);                             \
      gload_lds16(W + (size_t)row_ * K2 + gc_,                               \
                  (char*)Bs[b] + it * 4096 + t * 16);                        \
    }                                                                        \
  } while (0)

  floatx4 acc[2][4];
  const floatx4 z = {0.f, 0.f, 0.f, 0.f};
#pragma unroll
  for (int i = 0; i < 2; i++)
#pragma unroll
    for (int j = 0; j < 4; j++) acc[i][j] = z;

  G2STAGE(0, 0);
#pragma clang loop unroll(disable)
  for (int kt = 0; kt < 16; ++kt) {
    const int cur = kt & 1;
    if (kt + 1 < 16) {
      G2STAGE(cur ^ 1, kt + 1);
      asm volatile("s_waitcnt vmcnt(9)" ::: "memory");   // cur tile landed
    } else {
      asm volatile("s_waitcnt vmcnt(0)" ::: "memory");
    }
    __builtin_amdgcn_s_barrier();
    asm volatile("" ::: "memory");
#pragma unroll
    for (int ks = 0; ks < 2; ++ks) {
      short8 af[2], bfr[4];
      const int kq = ks * 4 + quad;
#pragma unroll
      for (int mt = 0; mt < 2; ++mt) {
        int row = mt * 16 + r15;
        af[mt] = *(const short8*)((const char*)As[cur] + row * 128 +
                                  ((kq ^ (row & 7)) << 4));
      }
#pragma unroll
      for (int nt = 0; nt < 4; ++nt) {
        int row = wave * 64 + nt * 16 + r15;
        bfr[nt] = *(const short8*)((const char*)Bs[cur] + row * 128 +
                                   ((kq ^ (row & 7)) << 4));
      }
#pragma unroll
      for (int mt = 0; mt < 2; ++mt)
#pragma unroll
        for (int nt = 0; nt < 4; ++nt)
          acc[mt][nt] = __builtin_amdgcn_mfma_f32_16x16x32_bf16(
              af[mt], bfr[nt], acc[mt][nt], 0, 0, 0);
    }
    asm volatile("" ::: "memory");
    __builtin_amdgcn_s_barrier();   // readers done before next overwrite
  }
#undef G2STAGE

  const int gcol0 = wave * 64;
#pragma unroll
  for (int mt = 0; mt < 2; ++mt) {
#pragma unroll
    for (int i = 0; i < 4; ++i) {
      size_t gr = (size_t)mrow0 + mt * 16 + quad * 4 + i;
      size_t rb = gr * (size_t)N2;
#pragma unroll
      for (int nt = 0; nt < 4; ++nt) {
        int gc = gcol0 + nt * 16 + r15;
        unsafeAtomicAdd(&out[rb + gc], acc[mt][nt][i]);
      }
    }
  }
}

extern "C" void kernel_launch(void* const* d_in, const int* in_sizes, int n_in,
                              void* d_out, int out_size, void* d_ws,
                              size_t ws_size, hipStream_t stream) {
  const float* x     = (const float*)d_in[0];  // [8192, 256]
  const float* h     = (const float*)d_in[1];  // [8192, 2048]
  const float* W_i2h = (const float*)d_in[2];  // [2048, 2304]
  const float* b_i2h = (const float*)d_in[3];  // [2048]
  const float* W_h2o = (const float*)d_in[4];  // [256, 2048]
  const float* b_h2o = (const float*)d_in[5];  // [256]

  float* out       = (float*)d_out;                    // [8192, 256]
  float* hnew_f32  = out + (size_t)BATCH * N2;         // [8192, 2048]

  bf16* comb   = (bf16*)d_ws;                          // 8192*2304
  bf16* Wi2h_b = comb + (size_t)BATCH * K1;            // 2048*2304
  bf16* Wh2o_b = Wi2h_b + (size_t)N1 * K1;             // 256*2048
  bf16* hnew_b = Wh2o_b + (size_t)N2 * K2;             // 8192*2048

  // fused converters + bias seed (before gemm2's atomic accumulation)
  prep<<<(SEG0 + SEG1 + SEG2 + SEG3) / 256, 256, 0, stream>>>(
      x, h, W_i2h, W_h2o, b_h2o, comb, Wi2h_b, Wh2o_b, out);

  // GEMM1: 256x256 tiles, grid 32 x 8 = 256 blocks (1 per CU)
  gemm1_tanh<<<dim3(BATCH / 256, N1 / 256), 512, 0, stream>>>(
      comb, Wi2h_b, b_i2h, hnew_f32, hnew_b);

  // GEMM2: grid 256 x 2 (M-tiles x K-splits), atomic accumulate
  gemm2_out<<<dim3(BATCH / 32, 2), 256, 0, stream>>>(hnew_b, Wh2o_b, out);
}

// Round 5
// 256.057 us; speedup vs baseline: 1.0162x; 1.0162x over previous
//
#include <hip/hip_runtime.h>
#include <hip/hip_bf16.h>
#include <cstdint>

using bf16 = __hip_bfloat16;
typedef __attribute__((ext_vector_type(8))) short short8;
typedef __attribute__((ext_vector_type(4))) float floatx4;

// Problem constants
static constexpr int BATCH = 8192;
static constexpr int K1    = 2304;   // OBS + NH
static constexpr int N1    = 2048;   // NH
static constexpr int K2    = 2048;   // NH
static constexpr int N2    = 256;    // 2*LAT
static constexpr int KT1   = K1 / 64;  // 36 K-tiles of 64

__device__ __forceinline__ void gload_lds16(const void* g, void* l) {
  __builtin_amdgcn_global_load_lds(
      (const __attribute__((address_space(1))) void*)g,
      (__attribute__((address_space(3))) void*)l, 16, 0, 0);
}

// tanh(x) = 1 - 2/(1+e^{2x}); exp2-based, saturates to +/-1, err ~1e-6
__device__ __forceinline__ float fast_tanh(float x) {
  float e = __builtin_amdgcn_exp2f(x * 2.8853900817779268f);  // 2*log2(e)
  return 1.0f - 2.0f * __builtin_amdgcn_rcpf(e + 1.0f);
}

__device__ __forceinline__ short8 cvt8(const float* src) {
  float4 a = ((const float4*)src)[0];
  float4 b = ((const float4*)src)[1];
  union { short8 v; bf16 e[8]; } u;
  u.e[0] = __float2bfloat16(a.x); u.e[1] = __float2bfloat16(a.y);
  u.e[2] = __float2bfloat16(a.z); u.e[3] = __float2bfloat16(a.w);
  u.e[4] = __float2bfloat16(b.x); u.e[5] = __float2bfloat16(b.y);
  u.e[6] = __float2bfloat16(b.z); u.e[7] = __float2bfloat16(b.w);
  return u.v;
}

// ------- fused prep: cat(x,h)->bf16, W_i2h->bf16, W_h2o->bf16, bias seed ---
static constexpr int SEG0 = BATCH * (K1 / 8);          // 2,359,296
static constexpr int SEG1 = N1 * K1 / 8;               //   589,824
static constexpr int SEG2 = N2 * K2 / 8;               //    65,536
static constexpr int SEG3 = BATCH * (N2 / 4);          //   524,288 (bias seed)
__global__ __launch_bounds__(256) void prep(
    const float* __restrict__ x, const float* __restrict__ h,
    const float* __restrict__ W1, const float* __restrict__ W2,
    const float* __restrict__ b2,
    bf16* __restrict__ comb, bf16* __restrict__ W1b, bf16* __restrict__ W2b,
    float* __restrict__ outp) {
  int i = blockIdx.x * 256 + threadIdx.x;
  if (i < SEG0) {
    int row  = i / 288;
    int slot = i - row * 288;
    const float* src = (slot < 32) ? (x + (size_t)row * 256 + slot * 8)
                                   : (h + (size_t)row * 2048 + (slot - 32) * 8);
    *(short8*)(comb + (size_t)row * 2304 + slot * 8) = cvt8(src);
  } else if (i < SEG0 + SEG1) {
    int j = i - SEG0;
    *(short8*)(W1b + (size_t)j * 8) = cvt8(W1 + (size_t)j * 8);
  } else if (i < SEG0 + SEG1 + SEG2) {
    int j = i - (SEG0 + SEG1);
    *(short8*)(W2b + (size_t)j * 8) = cvt8(W2 + (size_t)j * 8);
  } else {
    int j = i - (SEG0 + SEG1 + SEG2);   // out = bias broadcast (gemm2 seed)
    float4 b = ((const float4*)b2)[j & 63];
    ((float4*)outp)[j] = b;
  }
}

// ---------------- GEMM1: h_new = tanh(A @ W^T + bias) ----------------
// 256x256 tile, BK=64, 8 waves (2M x 4N), 128x64 per wave, 16x16x32 MFMA.
// PIPELINED-READ schedule (R5): 4 phases/K-tile, ONE barrier per phase.
// Phase p issues the ds_reads for phase p+1 (into the alternate reg set),
// so the LDS drain of p+1's operands runs UNDER phase p's 16-MFMA cluster.
// Phase p's own operands were issued in p-1 -> lgkm wait is ~free.
//
// Per phase: [reads_{p+1} (4 or 8 ds_read_b128)] -> [STG 2 gload_lds]
//   -> (even phases: vmcnt(6)) -> lgkm(4|8) -> 16 MFMA -> s_barrier.
//
// Stage schedule (iteration n=2*t2; buf0 even tiles, buf1 odd):
//   ph0: buf1.A.kh1<-n+1   ph1: buf1.B.kh1<-n+1
//   ph2: buf0.A.kh0<-n+2   ph3: buf0.B.kh0<-n+2
//   ph4: buf0.A.kh1<-n+2   ph5: buf0.B.kh1<-n+2
//   ph6: buf1.A.kh0<-n+3   ph7: buf1.B.kh0<-n+3
// vmcnt(6) at even phases retires exactly the 2-phase-old stage pair whose
// region is read-issued one phase later (outstanding trace: 10 -> 6 each
// even phase, prologue included).  Hazard audit:
//  I2 (stage before read): region staged at s is vmcnt-retired at the next
//      even phase <= issue-1 and barrier'd before its reads are issued.
//  I1 (read before overwrite): reads of a region complete (lgkm) in phase q,
//      before B_q; the next stage of that region issues earliest q+1 > B_q.
//  WAR on frag regs: consume-set != issue-set every phase (A/B alternate).
__global__ __launch_bounds__(512, 2) void gemm1_tanh(
    const bf16* __restrict__ A, const bf16* __restrict__ W,
    const float* __restrict__ bias,
    float* __restrict__ hf32, bf16* __restrict__ hb16) {
  __shared__ bf16 lds[2][2][2][8192];   // [buf][A/B][kh][256 rows x 32] 128 KiB
  const int t    = threadIdx.x;         // 0..511
  const int lane = t & 63;
  const int wave = t >> 6;              // 0..7
  const int wm   = (wave >> 2) * 128;   // 0 or 128
  const int wn   = (wave & 3) * 64;     // 0,64,128,192
  const int quad = lane >> 4;
  const int r15  = lane & 15;

  // LDS read bases (byte offsets within one [kh] bank of 16384 B)
  const int swz   = ((quad ^ ((r15 >> 1) & 3)) << 4);
  const int baseA = wm * 64 + r15 * 64 + swz;            // + mtg*4096 + mt*1024
  const int baseB = 32768 + wn * 64 + r15 * 64 + swz;    // + nt*1024

  // staging: thread covers row r = half*128 + (t>>2), 16B slot s = t&3,
  // pre-swizzled global col so LDS dest stays linear (dest = half*8192 + t*16)
  const int srow  = t >> 2;             // 0..127
  const int sslot = t & 3;
  const int sq    = (sslot ^ ((srow >> 1) & 3)) * 8;  // elem offset in K-half

  const size_t Abase = (size_t)blockIdx.x * 256 * K1;
  const size_t Bbase = (size_t)blockIdx.y * 256 * K1;
  const size_t gA0 = Abase + (size_t)srow * K1 + sq;
  const size_t gA1 = Abase + (size_t)(srow + 128) * K1 + sq;
  const size_t gB0 = Bbase + (size_t)srow * K1 + sq;
  const size_t gB1 = Bbase + (size_t)(srow + 128) * K1 + sq;
  const int d0 = t * 16, d1 = 8192 + t * 16;   // LDS byte offsets
  char* const ldsb = (char*)lds;

  // stage one (buf, mat, kh) region from K-tile skt (clamped): 2 gloads
#define STG(sb, mat_, skh, skt) do {                                         \
    const int ktc_ = ((skt) < KT1 ? (skt) : (KT1 - 1));                      \
    const size_t ko_ = (size_t)ktc_ * 64 + (skh) * 32;                       \
    char* const la_ = ldsb + ((sb) << 16) + ((mat_) * 32768) + ((skh) << 14);\
    const bf16* g0_ = (mat_) ? (W + gB0 + ko_) : (A + gA0 + ko_);            \
    const bf16* g1_ = (mat_) ? (W + gB1 + ko_) : (A + gA1 + ko_);            \
    gload_lds16(g0_, la_ + d0);                                              \
    gload_lds16(g1_, la_ + d1);                                              \
  } while (0)

  floatx4 acc[8][4];
  const floatx4 z = {0.f, 0.f, 0.f, 0.f};
#pragma unroll
  for (int i = 0; i < 8; i++)
#pragma unroll
    for (int j = 0; j < 4; j++) acc[i][j] = z;

  short8 afA[4], afB[4], bfA[4], bfB[4];   // double-buffered fragment sets

  // prologue: buf0 kh0+kh1 <- tile 0 (A+B), buf1 kh0 <- tile 1 (A+B)
  STG(0, 0, 0, 0); STG(0, 1, 0, 0);
  STG(0, 0, 1, 0); STG(0, 1, 1, 0);
  STG(1, 0, 0, 1); STG(1, 1, 0, 1);
  asm volatile("s_waitcnt vmcnt(8)" ::: "memory");   // buf0.kh0 landed
  __builtin_amdgcn_s_barrier();
  __builtin_amdgcn_sched_barrier(0);
  {  // pre-issue reads for ph0: (buf0, ks0, mtg0) -> afA, bfA
#pragma unroll
    for (int mt = 0; mt < 4; ++mt)
      afA[mt] = *(const short8*)(ldsb + baseA + mt * 1024);
#pragma unroll
    for (int nt = 0; nt < 4; ++nt)
      bfA[nt] = *(const short8*)(ldsb + baseB + nt * 1024);
  }

  // PH: consume (ccb,cks,cmtg) from AFC/BFC; issue reads (rcb,rks,rmtg) into
  // AFN (and BFN if RB); stage (sb,smat,skh,skt); VMW: vmcnt(6); lgkm(LGS).
#define PH(ccb, cks, cmtg, AFC, BFC, rcb, rks, rmtg, AFN, BFN, RB,           \
           sb, smat, skh, skt, VMW, LGS) do {                                \
    const char* Lr_ = ldsb + ((rcb) << 16) + ((rks) << 14);                  \
    _Pragma("unroll")                                                        \
    for (int mt = 0; mt < 4; ++mt)                                           \
      AFN[mt] = *(const short8*)(Lr_ + baseA + (rmtg) * 4096 + mt * 1024);   \
    if (RB) {                                                                \
      _Pragma("unroll")                                                      \
      for (int nt = 0; nt < 4; ++nt)                                         \
        BFN[nt] = *(const short8*)(Lr_ + baseB + nt * 1024);                 \
    }                                                                        \
    STG(sb, smat, skh, skt);                                                 \
    __builtin_amdgcn_sched_barrier(0);                                       \
    if (VMW) asm volatile("s_waitcnt vmcnt(6)" ::: "memory");                \
    asm volatile("s_waitcnt lgkmcnt(" LGS ")" ::: "memory");                 \
    __builtin_amdgcn_sched_barrier(0);                                       \
    __builtin_amdgcn_s_setprio(1);                                           \
    _Pragma("unroll")                                                        \
    for (int mt = 0; mt < 4; ++mt)                                           \
      _Pragma("unroll")                                                      \
      for (int nt = 0; nt < 4; ++nt)                                         \
        acc[(cmtg) * 4 + mt][nt] = __builtin_amdgcn_mfma_f32_16x16x32_bf16(  \
            AFC[mt], BFC[nt], acc[(cmtg) * 4 + mt][nt], 0, 0, 0);            \
    __builtin_amdgcn_s_setprio(0);                                           \
    __builtin_amdgcn_s_barrier();                                            \
    __builtin_amdgcn_sched_barrier(0);                                       \
  } while (0)

#pragma clang loop unroll(disable)
  for (int t2 = 0; t2 < KT1 / 2; ++t2) {
    const int n = 2 * t2;
    PH(0, 0, 0, afA, bfA,  0, 0, 1, afB, bfB, 0,  1, 0, 1, n + 1, 1, "4");
    PH(0, 0, 1, afB, bfA,  0, 1, 0, afA, bfB, 1,  1, 1, 1, n + 1, 0, "8");
    PH(0, 1, 0, afA, bfB,  0, 1, 1, afB, bfA, 0,  0, 0, 0, n + 2, 1, "4");
    PH(0, 1, 1, afB, bfB,  1, 0, 0, afA, bfA, 1,  0, 1, 0, n + 2, 0, "8");
    PH(1, 0, 0, afA, bfA,  1, 0, 1, afB, bfB, 0,  0, 0, 1, n + 2, 1, "4");
    PH(1, 0, 1, afB, bfA,  1, 1, 0, afA, bfB, 1,  0, 1, 1, n + 2, 0, "8");
    PH(1, 1, 0, afA, bfB,  1, 1, 1, afB, bfA, 0,  1, 0, 0, n + 3, 1, "4");
    PH(1, 1, 1, afB, bfB,  0, 0, 0, afA, bfA, 1,  1, 1, 0, n + 3, 0, "8");
  }
#undef PH
#undef STG

  // epilogue: bias + fast tanh, dual-write f32 (output) and bf16 (GEMM2 input)
  const int gcol0 = blockIdx.y * 256 + wn;
  float bv[4];
#pragma unroll
  for (int nt = 0; nt < 4; ++nt) bv[nt] = bias[gcol0 + nt * 16 + r15];
  const size_t grow0 = (size_t)blockIdx.x * 256 + wm;
#pragma unroll
  for (int mt = 0; mt < 8; ++mt) {
#pragma unroll
    for (int i = 0; i < 4; ++i) {
      const size_t gr = grow0 + mt * 16 + quad * 4 + i;
      const size_t rb = gr * (size_t)N1;
#pragma unroll
      for (int nt = 0; nt < 4; ++nt) {
        const int gc = gcol0 + nt * 16 + r15;
        float v = fast_tanh(acc[mt][nt][i] + bv[nt]);
        hf32[rb + gc] = v;
        hb16[rb + gc] = __float2bfloat16(v);
      }
    }
  }
}

// ---------------- GEMM2: out += h_new @ W_h2o^T (split-K=2) -------------
// Double-buffered: stage(next) issued before compute(cur); counted vmcnt(9)
// (never 0 mid-loop) + raw barriers so prefetch stays in flight.
__global__ __launch_bounds__(256) void gemm2_out(
    const bf16* __restrict__ A, const bf16* __restrict__ W,
    float* __restrict__ out) {
  __shared__ bf16 As[2][32 * 64];    //  8 KB
  __shared__ bf16 Bs[2][256 * 64];   // 64 KB
  const int t    = threadIdx.x;
  const int lane = t & 63;
  const int wave = t >> 6;
  const int quad = lane >> 4;
  const int r15  = lane & 15;
  const int srow = t >> 3;   // 0..31
  const int sc   = t & 7;

  const int mrow0 = blockIdx.x * 32;
  const int kbase = blockIdx.y * (K2 / 2);   // 0 or 1024

#define G2STAGE(b, kt) do {                                                  \
    const int k0_ = kbase + (kt) * 64;                                       \
    {                                                                        \
      int gc_ = k0_ + ((sc ^ (srow & 7)) << 3);                              \
      gload_lds16(A + (size_t)(mrow0 + srow) * K2 + gc_,                     \
                  (char*)As[b] + t * 16);                                    \
    }                                                                        \
    _Pragma("unroll")                                                        \
    for (int it = 0; it < 8; ++it) {                                         \
      int row_ = it * 32 + srow;                                             \
      int gc_  = k0_ + ((sc ^ (row_ & 7)) << 3);                             \
      gload_lds16(W + (size_t)row_ * K2 + gc_,                               \
                  (char*)Bs[b] + it * 4096 + t * 16);                        \
    }                                                                        \
  } while (0)

  floatx4 acc[2][4];
  const floatx4 z = {0.f, 0.f, 0.f, 0.f};
#pragma unroll
  for (int i = 0; i < 2; i++)
#pragma unroll
    for (int j = 0; j < 4; j++) acc[i][j] = z;

  G2STAGE(0, 0);
#pragma clang loop unroll(disable)
  for (int kt = 0; kt < 16; ++kt) {
    const int cur = kt & 1;
    if (kt + 1 < 16) {
      G2STAGE(cur ^ 1, kt + 1);
      asm volatile("s_waitcnt vmcnt(9)" ::: "memory");   // cur tile landed
    } else {
      asm volatile("s_waitcnt vmcnt(0)" ::: "memory");
    }
    __builtin_amdgcn_s_barrier();
    asm volatile("" ::: "memory");
#pragma unroll
    for (int ks = 0; ks < 2; ++ks) {
      short8 af[2], bfr[4];
      const int kq = ks * 4 + quad;
#pragma unroll
      for (int mt = 0; mt < 2; ++mt) {
        int row = mt * 16 + r15;
        af[mt] = *(const short8*)((const char*)As[cur] + row * 128 +
                                  ((kq ^ (row & 7)) << 4));
      }
#pragma unroll
      for (int nt = 0; nt < 4; ++nt) {
        int row = wave * 64 + nt * 16 + r15;
        bfr[nt] = *(const short8*)((const char*)Bs[cur] + row * 128 +
                                   ((kq ^ (row & 7)) << 4));
      }
#pragma unroll
      for (int mt = 0; mt < 2; ++mt)
#pragma unroll
        for (int nt = 0; nt < 4; ++nt)
          acc[mt][nt] = __builtin_amdgcn_mfma_f32_16x16x32_bf16(
              af[mt], bfr[nt], acc[mt][nt], 0, 0, 0);
    }
    asm volatile("" ::: "memory");
    __builtin_amdgcn_s_barrier();   // readers done before next overwrite
  }
#undef G2STAGE

  const int gcol0 = wave * 64;
#pragma unroll
  for (int mt = 0; mt < 2; ++mt) {
#pragma unroll
    for (int i = 0; i < 4; ++i) {
      size_t gr = (size_t)mrow0 + mt * 16 + quad * 4 + i;
      size_t rb = gr * (size_t)N2;
#pragma unroll
      for (int nt = 0; nt < 4; ++nt) {
        int gc = gcol0 + nt * 16 + r15;
        unsafeAtomicAdd(&out[rb + gc], acc[mt][nt][i]);
      }
    }
  }
}

extern "C" void kernel_launch(void* const* d_in, const int* in_sizes, int n_in,
                              void* d_out, int out_size, void* d_ws,
                              size_t ws_size, hipStream_t stream) {
  const float* x     = (const float*)d_in[0];  // [8192, 256]
  const float* h     = (const float*)d_in[1];  // [8192, 2048]
  const float* W_i2h = (const float*)d_in[2];  // [2048, 2304]
  const float* b_i2h = (const float*)d_in[3];  // [2048]
  const float* W_h2o = (const float*)d_in[4];  // [256, 2048]
  const float* b_h2o = (const float*)d_in[5];  // [256]

  float* out       = (float*)d_out;                    // [8192, 256]
  float* hnew_f32  = out + (size_t)BATCH * N2;         // [8192, 2048]

  bf16* comb   = (bf16*)d_ws;                          // 8192*2304
  bf16* Wi2h_b = comb + (size_t)BATCH * K1;            // 2048*2304
  bf16* Wh2o_b = Wi2h_b + (size_t)N1 * K1;             // 256*2048
  bf16* hnew_b = Wh2o_b + (size_t)N2 * K2;             // 8192*2048

  // fused converters + bias seed (before gemm2's atomic accumulation)
  prep<<<(SEG0 + SEG1 + SEG2 + SEG3) / 256, 256, 0, stream>>>(
      x, h, W_i2h, W_h2o, b_h2o, comb, Wi2h_b, Wh2o_b, out);

  // GEMM1: 256x256 tiles, grid 32 x 8 = 256 blocks (1 per CU)
  gemm1_tanh<<<dim3(BATCH / 256, N1 / 256), 512, 0, stream>>>(
      comb, Wi2h_b, b_i2h, hnew_f32, hnew_b);

  // GEMM2: grid 256 x 2 (M-tiles x K-splits), atomic accumulate
  gemm2_out<<<dim3(BATCH / 32, 2), 256, 0, stream>>>(hnew_b, Wh2o_b, out);
}

// Round 7
// 255.456 us; speedup vs baseline: 1.0186x; 1.0024x over previous
//
#include <hip/hip_runtime.h>
#include <hip/hip_bf16.h>
#include <cstdint>

using bf16 = __hip_bfloat16;
typedef __attribute__((ext_vector_type(8))) short short8;
typedef __attribute__((ext_vector_type(4))) float floatx4;

// Problem constants
static constexpr int BATCH = 8192;
static constexpr int K1    = 2304;   // OBS + NH
static constexpr int N1    = 2048;   // NH
static constexpr int K2    = 2048;   // NH
static constexpr int N2    = 256;    // 2*LAT
static constexpr int KT1   = K1 / 64;  // 36 K-tiles of 64

__device__ __forceinline__ void gload_lds16(const void* g, void* l) {
  __builtin_amdgcn_global_load_lds(
      (const __attribute__((address_space(1))) void*)g,
      (__attribute__((address_space(3))) void*)l, 16, 0, 0);
}

// tanh(x) = 1 - 2/(1+e^{2x}); exp2-based, saturates to +/-1, err ~1e-6
__device__ __forceinline__ float fast_tanh(float x) {
  float e = __builtin_amdgcn_exp2f(x * 2.8853900817779268f);  // 2*log2(e)
  return 1.0f - 2.0f * __builtin_amdgcn_rcpf(e + 1.0f);
}

__device__ __forceinline__ short8 cvt8(const float* src) {
  float4 a = ((const float4*)src)[0];
  float4 b = ((const float4*)src)[1];
  union { short8 v; bf16 e[8]; } u;
  u.e[0] = __float2bfloat16(a.x); u.e[1] = __float2bfloat16(a.y);
  u.e[2] = __float2bfloat16(a.z); u.e[3] = __float2bfloat16(a.w);
  u.e[4] = __float2bfloat16(b.x); u.e[5] = __float2bfloat16(b.y);
  u.e[6] = __float2bfloat16(b.z); u.e[7] = __float2bfloat16(b.w);
  return u.v;
}

// ------- fused prep: cat(x,h)->bf16, W_i2h->bf16, W_h2o->bf16, bias seed ---
static constexpr int SEG0 = BATCH * (K1 / 8);          // 2,359,296
static constexpr int SEG1 = N1 * K1 / 8;               //   589,824
static constexpr int SEG2 = N2 * K2 / 8;               //    65,536
static constexpr int SEG3 = BATCH * (N2 / 4);          //   524,288 (bias seed)
__global__ __launch_bounds__(256) void prep(
    const float* __restrict__ x, const float* __restrict__ h,
    const float* __restrict__ W1, const float* __restrict__ W2,
    const float* __restrict__ b2,
    bf16* __restrict__ comb, bf16* __restrict__ W1b, bf16* __restrict__ W2b,
    float* __restrict__ outp) {
  int i = blockIdx.x * 256 + threadIdx.x;
  if (i < SEG0) {
    int row  = i / 288;
    int slot = i - row * 288;
    const float* src = (slot < 32) ? (x + (size_t)row * 256 + slot * 8)
                                   : (h + (size_t)row * 2048 + (slot - 32) * 8);
    *(short8*)(comb + (size_t)row * 2304 + slot * 8) = cvt8(src);
  } else if (i < SEG0 + SEG1) {
    int j = i - SEG0;
    *(short8*)(W1b + (size_t)j * 8) = cvt8(W1 + (size_t)j * 8);
  } else if (i < SEG0 + SEG1 + SEG2) {
    int j = i - (SEG0 + SEG1);
    *(short8*)(W2b + (size_t)j * 8) = cvt8(W2 + (size_t)j * 8);
  } else {
    int j = i - (SEG0 + SEG1 + SEG2);   // out = bias broadcast (atomic seed)
    float4 b = ((const float4*)b2)[j & 63];
    ((float4*)outp)[j] = b;
  }
}

// ---- reduce8: out = bias + sum_{by} part[by]  (partial-sum path) ----------
__global__ __launch_bounds__(256) void reduce8(
    const float* __restrict__ part, const float* __restrict__ bias,
    float* __restrict__ out) {
  int i = blockIdx.x * 256 + threadIdx.x;   // float4 index over [8192*256/4]
  float4 s = ((const float4*)bias)[i & 63];
#pragma unroll
  for (int b = 0; b < 8; ++b) {
    float4 p = ((const float4*)(part + (size_t)b * BATCH * N2))[i];
    s.x += p.x; s.y += p.y; s.z += p.z; s.w += p.w;
  }
  ((float4*)out)[i] = s;
}

// ---------------- GEMM1: h_new = tanh(A @ W^T + bias); FUSED GEMM2 --------
// K-loop identical to R5 (pipelined reads, 1 barrier/phase, counted vmcnt).
// Fused epilogue: block (bx,by)'s h-chunk [256r x 256c] is a k=256 slice of
// gemm2 (out = h_new @ W2^T). After tanh: store hf32, write bf16 h-tile to
// LDS (reuses the 128 KiB staging buffer; XOR-swizzle (col>>3)^(row&7) so
// 16-lane column reads are 2-way/free), mini-GEMM 256x256x256 with B = W2
// k-slice streamed from L2-resident W2b, then emit the partial:
//   MODE 1: plain stores to part[by] (reduce8 sums; avoids atomics)
//   MODE 0: unsafeAtomicAdd into bias-seeded out (ws-too-small fallback)
// R6 bug (absmax 2.85): MODE 1 store missed the blockIdx.y slab offset ->
// all 8 by-blocks raced into part[0], part[1..7] garbage. Fixed below.
template <int MODE>
__global__ __launch_bounds__(512, 2) void gemm1_tanh(
    const bf16* __restrict__ A, const bf16* __restrict__ W,
    const float* __restrict__ bias, const bf16* __restrict__ W2b,
    float* __restrict__ hf32, float* __restrict__ outp) {
  __shared__ __align__(16) char ldsb_s[131072];  // staging [2][2][2][16KB] / htile
  char* const ldsb = ldsb_s;
  const int t    = threadIdx.x;         // 0..511
  const int lane = t & 63;
  const int wave = t >> 6;              // 0..7
  const int wm   = (wave >> 2) * 128;   // 0 or 128
  const int wn   = (wave & 3) * 64;     // 0,64,128,192
  const int quad = lane >> 4;
  const int r15  = lane & 15;

  // LDS read bases (byte offsets within one [kh] bank of 16384 B)
  const int swz   = ((quad ^ ((r15 >> 1) & 3)) << 4);
  const int baseA = wm * 64 + r15 * 64 + swz;            // + mtg*4096 + mt*1024
  const int baseB = 32768 + wn * 64 + r15 * 64 + swz;    // + nt*1024

  // staging: thread covers row r = half*128 + (t>>2), 16B slot s = t&3,
  // pre-swizzled global col so LDS dest stays linear (dest = half*8192 + t*16)
  const int srow  = t >> 2;             // 0..127
  const int sslot = t & 3;
  const int sq    = (sslot ^ ((srow >> 1) & 3)) * 8;  // elem offset in K-half

  const size_t Abase = (size_t)blockIdx.x * 256 * K1;
  const size_t Bbase = (size_t)blockIdx.y * 256 * K1;
  const size_t gA0 = Abase + (size_t)srow * K1 + sq;
  const size_t gA1 = Abase + (size_t)(srow + 128) * K1 + sq;
  const size_t gB0 = Bbase + (size_t)srow * K1 + sq;
  const size_t gB1 = Bbase + (size_t)(srow + 128) * K1 + sq;
  const int d0 = t * 16, d1 = 8192 + t * 16;   // LDS byte offsets

  // stage one (buf, mat, kh) region from K-tile skt (clamped): 2 gloads
#define STG(sb, mat_, skh, skt) do {                                         \
    const int ktc_ = ((skt) < KT1 ? (skt) : (KT1 - 1));                      \
    const size_t ko_ = (size_t)ktc_ * 64 + (skh) * 32;                       \
    char* const la_ = ldsb + ((sb) << 16) + ((mat_) * 32768) + ((skh) << 14);\
    const bf16* g0_ = (mat_) ? (W + gB0 + ko_) : (A + gA0 + ko_);            \
    const bf16* g1_ = (mat_) ? (W + gB1 + ko_) : (A + gA1 + ko_);            \
    gload_lds16(g0_, la_ + d0);                                              \
    gload_lds16(g1_, la_ + d1);                                              \
  } while (0)

  floatx4 acc[8][4];
  const floatx4 z = {0.f, 0.f, 0.f, 0.f};
#pragma unroll
  for (int i = 0; i < 8; i++)
#pragma unroll
    for (int j = 0; j < 4; j++) acc[i][j] = z;

  short8 afA[4], afB[4], bfA[4], bfB[4];   // double-buffered fragment sets

  // prologue: buf0 kh0+kh1 <- tile 0 (A+B), buf1 kh0 <- tile 1 (A+B)
  STG(0, 0, 0, 0); STG(0, 1, 0, 0);
  STG(0, 0, 1, 0); STG(0, 1, 1, 0);
  STG(1, 0, 0, 1); STG(1, 1, 0, 1);
  asm volatile("s_waitcnt vmcnt(8)" ::: "memory");   // buf0.kh0 landed
  __builtin_amdgcn_s_barrier();
  __builtin_amdgcn_sched_barrier(0);
  {  // pre-issue reads for ph0: (buf0, ks0, mtg0) -> afA, bfA
#pragma unroll
    for (int mt = 0; mt < 4; ++mt)
      afA[mt] = *(const short8*)(ldsb + baseA + mt * 1024);
#pragma unroll
    for (int nt = 0; nt < 4; ++nt)
      bfA[nt] = *(const short8*)(ldsb + baseB + nt * 1024);
  }

  // PH: consume (ccb,cks,cmtg) from AFC/BFC; issue reads (rcb,rks,rmtg) into
  // AFN (and BFN if RB); stage (sb,smat,skh,skt); VMW: vmcnt(6); lgkm(LGS).
#define PH(ccb, cks, cmtg, AFC, BFC, rcb, rks, rmtg, AFN, BFN, RB,           \
           sb, smat, skh, skt, VMW, LGS) do {                                \
    const char* Lr_ = ldsb + ((rcb) << 16) + ((rks) << 14);                  \
    _Pragma("unroll")                                                        \
    for (int mt = 0; mt < 4; ++mt)                                           \
      AFN[mt] = *(const short8*)(Lr_ + baseA + (rmtg) * 4096 + mt * 1024);   \
    if (RB) {                                                                \
      _Pragma("unroll")                                                      \
      for (int nt = 0; nt < 4; ++nt)                                         \
        BFN[nt] = *(const short8*)(Lr_ + baseB + nt * 1024);                 \
    }                                                                        \
    STG(sb, smat, skh, skt);                                                 \
    __builtin_amdgcn_sched_barrier(0);                                       \
    if (VMW) asm volatile("s_waitcnt vmcnt(6)" ::: "memory");                \
    asm volatile("s_waitcnt lgkmcnt(" LGS ")" ::: "memory");                 \
    __builtin_amdgcn_sched_barrier(0);                                       \
    __builtin_amdgcn_s_setprio(1);                                           \
    _Pragma("unroll")                                                        \
    for (int mt = 0; mt < 4; ++mt)                                           \
      _Pragma("unroll")                                                      \
      for (int nt = 0; nt < 4; ++nt)                                         \
        acc[(cmtg) * 4 + mt][nt] = __builtin_amdgcn_mfma_f32_16x16x32_bf16(  \
            AFC[mt], BFC[nt], acc[(cmtg) * 4 + mt][nt], 0, 0, 0);            \
    __builtin_amdgcn_s_setprio(0);                                           \
    __builtin_amdgcn_s_barrier();                                            \
    __builtin_amdgcn_sched_barrier(0);                                       \
  } while (0)

#pragma clang loop unroll(disable)
  for (int t2 = 0; t2 < KT1 / 2; ++t2) {
    const int n = 2 * t2;
    PH(0, 0, 0, afA, bfA,  0, 0, 1, afB, bfB, 0,  1, 0, 1, n + 1, 1, "4");
    PH(0, 0, 1, afB, bfA,  0, 1, 0, afA, bfB, 1,  1, 1, 1, n + 1, 0, "8");
    PH(0, 1, 0, afA, bfB,  0, 1, 1, afB, bfA, 0,  0, 0, 0, n + 2, 1, "4");
    PH(0, 1, 1, afB, bfB,  1, 0, 0, afA, bfA, 1,  0, 1, 0, n + 2, 0, "8");
    PH(1, 0, 0, afA, bfA,  1, 0, 1, afB, bfB, 0,  0, 0, 1, n + 2, 1, "4");
    PH(1, 0, 1, afB, bfA,  1, 1, 0, afA, bfB, 1,  0, 1, 1, n + 2, 0, "8");
    PH(1, 1, 0, afA, bfB,  1, 1, 1, afB, bfA, 0,  1, 0, 0, n + 3, 1, "4");
    PH(1, 1, 1, afB, bfB,  0, 0, 0, afA, bfA, 1,  1, 1, 0, n + 3, 0, "8");
  }
#undef PH
#undef STG

  // ======================= fused epilogue ==============================
  // Drain all outstanding staging (tail prefetches) + frag reads, then the
  // staging LDS is dead and can be reused as the 256x256 bf16 h-tile.
  asm volatile("s_waitcnt vmcnt(0) lgkmcnt(0)" ::: "memory");
  __builtin_amdgcn_s_barrier();
  __builtin_amdgcn_sched_barrier(0);

  const int gcol0 = blockIdx.y * 256 + wn;
  float bv[4];
#pragma unroll
  for (int nt = 0; nt < 4; ++nt) bv[nt] = bias[gcol0 + nt * 16 + r15];
  const size_t grow0 = (size_t)blockIdx.x * 256 + wm;

  // htile byte addr: row*512 + swizzled 16B slot + in-slot offset
#define HB(row, col) ((row) * 512 + (((((col) >> 3) ^ ((row) & 7))) << 4) + \
                      (((col) & 7) << 1))
#pragma unroll
  for (int mt = 0; mt < 8; ++mt) {
#pragma unroll
    for (int i = 0; i < 4; ++i) {
      const int lrow = wm + mt * 16 + quad * 4 + i;
      const size_t rb = (grow0 + mt * 16 + quad * 4 + i) * (size_t)N1;
#pragma unroll
      for (int nt = 0; nt < 4; ++nt) {
        const int lcol = wn + nt * 16 + r15;
        float v = fast_tanh(acc[mt][nt][i] + bv[nt]);
        hf32[rb + gcol0 - wn + lcol] = v;   // = rb + blockIdx.y*256 + lcol
        *(bf16*)(ldsb + HB(lrow, lcol)) = __float2bfloat16(v);
      }
    }
  }
  asm volatile("s_waitcnt lgkmcnt(0)" ::: "memory");
  __builtin_amdgcn_s_barrier();
  __builtin_amdgcn_sched_barrier(0);

  // mini-GEMM: out2[256r x 256n2] += htile[256r x 256k] @ W2slice^T
  // wave owns 128r x 64n2 (same wm/wn); k = 256 (8 slices of 32).
#pragma unroll
  for (int i = 0; i < 8; i++)
#pragma unroll
    for (int j = 0; j < 4; j++) acc[i][j] = z;

  const bf16* w2base = W2b + (size_t)blockIdx.y * 256;   // k-slice of W2b[n2][2048]
#pragma unroll
  for (int ks = 0; ks < 8; ++ks) {
    short8 bq[4], aq[8];
#pragma unroll
    for (int nt = 0; nt < 4; ++nt)
      bq[nt] = *(const short8*)(w2base + (size_t)(wn + nt * 16 + r15) * 2048 +
                                ks * 32 + quad * 8);
#pragma unroll
    for (int mt = 0; mt < 8; ++mt) {
      const int row = wm + mt * 16 + r15;
      aq[mt] = *(const short8*)(ldsb + row * 512 +
                                ((((ks * 4 + quad) ^ (row & 7))) << 4));
    }
#pragma unroll
    for (int mt = 0; mt < 8; ++mt)
#pragma unroll
      for (int nt = 0; nt < 4; ++nt)
        acc[mt][nt] = __builtin_amdgcn_mfma_f32_16x16x32_bf16(
            aq[mt], bq[nt], acc[mt][nt], 0, 0, 0);
  }
#undef HB

  // emit partial (MODE 1: plain stores to part[by]; MODE 0: atomics to out)
  const size_t slab = (MODE == 1) ? (size_t)blockIdx.y * BATCH * N2 : 0;
#pragma unroll
  for (int mt = 0; mt < 8; ++mt) {
#pragma unroll
    for (int i = 0; i < 4; ++i) {
      const size_t gr = grow0 + mt * 16 + quad * 4 + i;
#pragma unroll
      for (int nt = 0; nt < 4; ++nt) {
        const int gc = wn + nt * 16 + r15;
        if (MODE == 0) {
          unsafeAtomicAdd(&outp[gr * N2 + gc], acc[mt][nt][i]);
        } else {
          outp[slab + gr * N2 + gc] = acc[mt][nt][i];
        }
      }
    }
  }
}

extern "C" void kernel_launch(void* const* d_in, const int* in_sizes, int n_in,
                              void* d_out, int out_size, void* d_ws,
                              size_t ws_size, hipStream_t stream) {
  const float* x     = (const float*)d_in[0];  // [8192, 256]
  const float* h     = (const float*)d_in[1];  // [8192, 2048]
  const float* W_i2h = (const float*)d_in[2];  // [2048, 2304]
  const float* b_i2h = (const float*)d_in[3];  // [2048]
  const float* W_h2o = (const float*)d_in[4];  // [256, 2048]
  const float* b_h2o = (const float*)d_in[5];  // [256]

  float* out       = (float*)d_out;                    // [8192, 256]
  float* hnew_f32  = out + (size_t)BATCH * N2;         // [8192, 2048]

  bf16* comb   = (bf16*)d_ws;                          // 8192*2304  (37.75 MB)
  bf16* Wi2h_b = comb + (size_t)BATCH * K1;            // 2048*2304  ( 9.44 MB)
  bf16* Wh2o_b = Wi2h_b + (size_t)N1 * K1;             // 256*2048   ( 1.00 MB)
  float* part  = (float*)(Wh2o_b + (size_t)N2 * K2);   // 8*8192*256 (67.11 MB)

  const size_t ws_needed = (size_t)BATCH * K1 * 2 + (size_t)N1 * K1 * 2 +
                           (size_t)N2 * K2 * 2 + (size_t)8 * BATCH * N2 * 4;
  const bool big_ws = ws_size >= ws_needed;

  // fused converters + bias seed (seed used by the atomic fallback path)
  prep<<<(SEG0 + SEG1 + SEG2 + SEG3) / 256, 256, 0, stream>>>(
      x, h, W_i2h, W_h2o, b_h2o, comb, Wi2h_b, Wh2o_b, out);

  if (big_ws) {
    // GEMM1 + fused GEMM2 partials; then reduce
    gemm1_tanh<1><<<dim3(BATCH / 256, N1 / 256), 512, 0, stream>>>(
        comb, Wi2h_b, b_i2h, Wh2o_b, hnew_f32, part);
    reduce8<<<(BATCH * N2 / 4) / 256, 256, 0, stream>>>(part, b_h2o, out);
  } else {
    // fallback: atomic accumulation into bias-seeded out
    gemm1_tanh<0><<<dim3(BATCH / 256, N1 / 256), 512, 0, stream>>>(
        comb, Wi2h_b, b_i2h, Wh2o_b, hnew_f32, out);
  }
}